// Round 1
// baseline (1300.151 us; speedup 1.0000x reference)
//
#include <hip/hip_runtime.h>
#include <hip/hip_bf16.h>
#include <math.h>

#define BB   16
#define CIN  256
#define HH   64
#define WW   64
#define COUT 256
#define NEXP 4
#define REDC 16
#define HW   (HH*WW)       // 4096
#define KTAP 9
#define CK   (CIN*KTAP)    // 2304

// ---------------- K1: global average pool: pooled[b*256+c] ----------------
__global__ void pool_kernel(const float* __restrict__ x, float* __restrict__ pooled) {
    int bc = blockIdx.x;                       // 0..4095 = b*256+c
    const float* xp = x + (size_t)bc * HW;
    float s = 0.f;
    for (int i = threadIdx.x; i < HW; i += 256) s += xp[i];
    #pragma unroll
    for (int off = 32; off > 0; off >>= 1) s += __shfl_down(s, off, 64);
    __shared__ float red[4];
    int lane = threadIdx.x & 63, wid = threadIdx.x >> 6;
    if (lane == 0) red[wid] = s;
    __syncthreads();
    if (threadIdx.x == 0) {
        pooled[bc] = (red[0] + red[1] + red[2] + red[3]) * (1.0f / HW);
    }
}

// ---------------- K2: routing MLP -> rw[b*1024 + k*256 + c] ----------------
__global__ void route_kernel(const float* __restrict__ pooled,
                             const float* __restrict__ w1, const float* __restrict__ b1,
                             const float* __restrict__ w2, const float* __restrict__ b2,
                             float* __restrict__ rw) {
    __shared__ float p_s[BB][CIN];
    __shared__ float r_s[BB][REDC];
    int tid = threadIdx.x;                     // 256 threads
    for (int i = tid; i < BB * CIN; i += 256) p_s[i >> 8][i & 255] = pooled[i];
    __syncthreads();
    {   // 256 entries of r: thread = (b,j)
        int b = tid >> 4, j = tid & 15;
        float acc = b1[j];
        for (int c = 0; c < CIN; ++c) acc += p_s[b][c] * w1[j * CIN + c];
        r_s[b][j] = fmaxf(acc, 0.f);
    }
    __syncthreads();
    for (int i = tid; i < BB * NEXP * CIN; i += 256) {
        int b = i >> 10, o2 = i & 1023;
        float acc = b2[o2];
        #pragma unroll
        for (int j = 0; j < REDC; ++j) acc += r_s[b][j] * w2[o2 * REDC + j];
        rw[i] = 1.f / (1.f + expf(-acc));
    }
}

// ------- K3: combined[b,o,c*9+ij] = sum_k rw[b,k,c] * weight[k,o,c,ij] -------
__global__ void combine_kernel(const float* __restrict__ rw,
                               const float* __restrict__ weight,
                               float* __restrict__ combined) {
    int idx = blockIdx.x * 256 + threadIdx.x;  // total B*COUT*CK = 9437184
    int b   = idx / (COUT * CK);
    int rem = idx % (COUT * CK);
    int o   = rem / CK;
    int t   = rem % CK;
    int c   = t / KTAP;
    float acc = 0.f;
    #pragma unroll
    for (int k = 0; k < NEXP; ++k)
        acc += rw[b * (NEXP * CIN) + k * CIN + c] *
               weight[((size_t)(k * COUT + o)) * CK + t];
    combined[idx] = acc;
}

// ---------------- K4: per-sample 3x3 conv, scalar fp32 ----------------
// block = (b, group of 4 output channels); 256 threads = 4 waves.
// Wave w handles rows 16w..16w+15, lane = column. LDS: padded 66x66 input
// channel (borders stay zero) + 4x2304 weights.
__global__ __launch_bounds__(256, 2)
void conv_kernel(const float* __restrict__ x, const float* __restrict__ combined,
                 float* __restrict__ out) {
    __shared__ float w_s[4 * CK];       // 36864 B
    __shared__ float x_s[66 * 66];      // 17424 B
    int blk = blockIdx.x;
    int b   = blk >> 6;                 // /64
    int og  = blk & 63;                 // output group: channels og*4..og*4+3
    int tid = threadIdx.x;

    const float* cb = combined + ((size_t)(b * COUT + og * 4)) * CK;
    for (int i = tid; i < 4 * CK; i += 256) w_s[i] = cb[i];
    for (int i = tid; i < 66 * 66; i += 256) x_s[i] = 0.f;

    int col  = tid & 63;                // lane-consecutive column
    int rg   = tid >> 6;                // wave id = row group
    int row0 = rg << 4;

    float acc[4][16];
    #pragma unroll
    for (int oo = 0; oo < 4; ++oo)
        #pragma unroll
        for (int h = 0; h < 16; ++h) acc[oo][h] = 0.f;

    const float* xb = x + (size_t)b * CIN * HW;
    __syncthreads();

    for (int c = 0; c < CIN; ++c) {
        // stage channel c into padded LDS (x row r -> lds row r+1, col+1)
        const float* xc = xb + (size_t)c * HW;
        #pragma unroll
        for (int k = 0; k < 16; ++k) {
            int idx = tid + k * 256;
            x_s[(idx >> 6) * 66 + (idx & 63) + 67] = xc[idx];
        }
        float wr[4][9];
        #pragma unroll
        for (int oo = 0; oo < 4; ++oo)
            #pragma unroll
            for (int t9 = 0; t9 < 9; ++t9) wr[oo][t9] = w_s[oo * CK + c * 9 + t9];
        __syncthreads();

        // rolling 3-row window; base = lds(row0, col) = x(row0-1, col-1)
        int base = row0 * 66 + col;
        float xm0 = x_s[base],      xm1 = x_s[base + 1],  xm2 = x_s[base + 2];
        float xc0 = x_s[base + 66], xc1 = x_s[base + 67], xc2 = x_s[base + 68];
        #pragma unroll
        for (int hh = 0; hh < 16; ++hh) {
            int nb = base + (hh + 2) * 66;
            float xn0 = x_s[nb], xn1 = x_s[nb + 1], xn2 = x_s[nb + 2];
            #pragma unroll
            for (int oo = 0; oo < 4; ++oo) {
                float a = acc[oo][hh];
                a = fmaf(wr[oo][0], xm0, a);
                a = fmaf(wr[oo][1], xm1, a);
                a = fmaf(wr[oo][2], xm2, a);
                a = fmaf(wr[oo][3], xc0, a);
                a = fmaf(wr[oo][4], xc1, a);
                a = fmaf(wr[oo][5], xc2, a);
                a = fmaf(wr[oo][6], xn0, a);
                a = fmaf(wr[oo][7], xn1, a);
                a = fmaf(wr[oo][8], xn2, a);
                acc[oo][hh] = a;
            }
            xm0 = xc0; xm1 = xc1; xm2 = xc2;
            xc0 = xn0; xc1 = xn1; xc2 = xn2;
        }
        __syncthreads();
    }

    #pragma unroll
    for (int oo = 0; oo < 4; ++oo) {
        float* op = out + ((size_t)(b * COUT + og * 4 + oo)) * HW;
        #pragma unroll
        for (int hh = 0; hh < 16; ++hh)
            op[(row0 + hh) * 64 + col] = acc[oo][hh];
    }
}

extern "C" void kernel_launch(void* const* d_in, const int* in_sizes, int n_in,
                              void* d_out, int out_size, void* d_ws, size_t ws_size,
                              hipStream_t stream) {
    const float* x      = (const float*)d_in[0];
    const float* w1     = (const float*)d_in[1];
    const float* b1     = (const float*)d_in[2];
    const float* w2     = (const float*)d_in[3];
    const float* b2     = (const float*)d_in[4];
    const float* weight = (const float*)d_in[5];
    float* out = (float*)d_out;

    float* ws       = (float*)d_ws;
    float* pooled   = ws;                         // 4096
    float* rw       = ws + 4096;                  // 16384
    float* combined = ws + 4096 + 16384;          // 9437184 floats (~36 MB)

    pool_kernel<<<BB * CIN, 256, 0, stream>>>(x, pooled);
    route_kernel<<<1, 256, 0, stream>>>(pooled, w1, b1, w2, b2, rw);
    combine_kernel<<<(BB * COUT * CK) / 256, 256, 0, stream>>>(rw, weight, combined);
    conv_kernel<<<BB * (COUT / 4), 256, 0, stream>>>(x, combined, out);
}

// Round 2
// 223.095 us; speedup vs baseline: 5.8278x; 5.8278x over previous
//
#include <hip/hip_runtime.h>
#include <hip/hip_bf16.h>
#include <math.h>

#define BB   16
#define CIN  256
#define HH   64
#define WW   64
#define COUT 256
#define NEXP 4
#define REDC 16
#define HW   (HH*WW)       // 4096

typedef __attribute__((ext_vector_type(8))) short short8;
typedef __attribute__((ext_vector_type(4))) float f32x4;

#define AS1 __attribute__((address_space(1)))
#define AS3 __attribute__((address_space(3)))

__device__ __forceinline__ void gld_lds16(void* lds, const void* gp) {
    __builtin_amdgcn_global_load_lds((const AS1 unsigned int*)gp,
                                     (AS3 unsigned int*)lds, 16, 0, 0);
}

// ---------------- K1: global average pool: pooled[b*256+c] ----------------
__global__ void pool_kernel(const float* __restrict__ x, float* __restrict__ pooled) {
    int bc = blockIdx.x;
    const float* xp = x + (size_t)bc * HW;
    float s = 0.f;
    for (int i = threadIdx.x; i < HW; i += 256) s += xp[i];
    #pragma unroll
    for (int off = 32; off > 0; off >>= 1) s += __shfl_down(s, off, 64);
    __shared__ float red[4];
    int lane = threadIdx.x & 63, wid = threadIdx.x >> 6;
    if (lane == 0) red[wid] = s;
    __syncthreads();
    if (threadIdx.x == 0)
        pooled[bc] = (red[0] + red[1] + red[2] + red[3]) * (1.0f / HW);
}

// ---------------- K2: routing MLP -> rw[b*1024 + k*256 + c] ----------------
__global__ void route_kernel(const float* __restrict__ pooled,
                             const float* __restrict__ w1, const float* __restrict__ b1,
                             const float* __restrict__ w2, const float* __restrict__ b2,
                             float* __restrict__ rw) {
    __shared__ float p_s[BB][CIN];
    __shared__ float r_s[BB][REDC];
    int tid = threadIdx.x;
    for (int i = tid; i < BB * CIN; i += 256) p_s[i >> 8][i & 255] = pooled[i];
    __syncthreads();
    {
        int b = tid >> 4, j = tid & 15;
        float acc = b1[j];
        for (int c = 0; c < CIN; ++c) acc += p_s[b][c] * w1[j * CIN + c];
        r_s[b][j] = fmaxf(acc, 0.f);
    }
    __syncthreads();
    for (int i = tid; i < BB * NEXP * CIN; i += 256) {
        int b = i >> 10, o2 = i & 1023;
        float acc = b2[o2];
        #pragma unroll
        for (int j = 0; j < REDC; ++j) acc += r_s[b][j] * w2[o2 * REDC + j];
        rw[i] = 1.f / (1.f + expf(-acc));
    }
}

// ------- K3: combined weights in MFMA fragment layout, bf16 -------
// cw flat index: (((((b*4+ot)*8+chunk)*9+t9)*4+g)*512 + o_loc*8 + c8
// value = sum_k rw[b,k,c] * weight[k, o, c, t9],  c = chunk*32+g*8+c8, o = ot*64+o_loc
__global__ void combine_kernel(const float* __restrict__ rw,
                               const float* __restrict__ weight,
                               ushort* __restrict__ cw) {
    int cb = blockIdx.x;          // 288 blocks = (ot 4) x (chunk 8) x (t9 9)
    int t9 = cb % 9;
    int tmp = cb / 9;
    int chunk = tmp & 7;
    int ot = tmp >> 3;
    __shared__ float rw_s[BB][NEXP][32];
    int tid = threadIdx.x;
    for (int i = tid; i < BB * NEXP * 32; i += 256) {
        int b = i >> 7, r = i & 127, k = r >> 5, cc = r & 31;
        rw_s[b][k][cc] = rw[b * 1024 + k * 256 + chunk * 32 + cc];
    }
    __syncthreads();
    for (int h = 0; h < 2; ++h) {
        int t = h * 256 + tid;            // 0..511 = o_loc*8 + c8
        int o_loc = t >> 3, c8 = t & 7;
        int o = ot * 64 + o_loc;
        #pragma unroll
        for (int g = 0; g < 4; ++g) {
            int c = chunk * 32 + g * 8 + c8;
            int cl = g * 8 + c8;
            float w0 = weight[((size_t)(0 * COUT + o) * CIN + c) * 9 + t9];
            float w1 = weight[((size_t)(1 * COUT + o) * CIN + c) * 9 + t9];
            float w2 = weight[((size_t)(2 * COUT + o) * CIN + c) * 9 + t9];
            float w3 = weight[((size_t)(3 * COUT + o) * CIN + c) * 9 + t9];
            for (int b = 0; b < BB; ++b) {
                float acc = rw_s[b][0][cl] * w0 + rw_s[b][1][cl] * w1 +
                            rw_s[b][2][cl] * w2 + rw_s[b][3][cl] * w3;
                __hip_bfloat16 hv = __float2bfloat16(acc);
                size_t idx = (((size_t)((b * 4 + ot) * 8 + chunk) * 9 + t9) * 4 + g) * 512 + t;
                cw[idx] = *(ushort*)&hv;
            }
        }
    }
}

// ---------------- K4: MFMA implicit-GEMM conv ----------------
// block: 256 thr (4 waves). tile: 64 out-ch x (8 rows x 64 cols). wave: 64 x 128.
// LDS: xs = x tile [s=row*66+col][32 c] bf16, 16B-slot XOR-swizzled; as = A frags.
__global__ __launch_bounds__(256, 2)
void conv_mfma(const float* __restrict__ x, const ushort* __restrict__ cw,
               float* __restrict__ out) {
    __shared__ unsigned int xs[10560];   // 660 s * 16 words = 42240 B
    __shared__ unsigned int as[9216];    // 36 slots * 64 o * 16 B = 36864 B

    int hw = blockIdx.x;
    int L = (hw & 7) * 64 + (hw >> 3);   // XCD-chunked swizzle (512 = 8*64)
    int b  = L >> 5;
    int rt = (L >> 2) & 7;
    int ot = L & 3;
    int r0 = rt * 8, o0 = ot * 64;
    int tid  = threadIdx.x;
    int lane = tid & 63, wid = tid >> 6;
    int l15  = lane & 15, g = lane >> 4;

    for (int i = tid; i < 10560; i += 256) xs[i] = 0;

    f32x4 acc[4][8];
    #pragma unroll
    for (int mi = 0; mi < 4; ++mi)
        #pragma unroll
        for (int f = 0; f < 8; ++f) acc[mi][f] = (f32x4)0.f;

    const float*  xb = x  + (size_t)b * CIN * HW;
    const ushort* Ab = cw + (size_t)((b * 4 + ot) * 8) * 18432;

    __syncthreads();

    for (int chunk = 0; chunk < 8; ++chunk) {
        // ---- stage A: contiguous 36 KB -> LDS via global_load_lds ----
        const ushort* Ac = Ab + (size_t)chunk * 18432;
        #pragma unroll
        for (int k2 = 0; k2 < 9; ++k2) {
            int blk16 = (k2 * 4 + wid);                  // 1 KB unit
            gld_lds16(&as[blk16 * 256],
                      (const char*)Ac + (size_t)blk16 * 1024 + lane * 16);
        }
        // ---- stage x: 32 channels, 10 rows x 64 cols, transpose+bf16 ----
        for (int i = 0; i < 40; ++i) {
            int q = i * 4 + wid;                 // wave-uniform 0..159
            int p = q / 10;                      // c-pair 0..15
            int row = q - p * 10;                // 0..9
            int grow = r0 - 1 + row;
            int c0 = chunk * 32 + p * 2;
            float lo = 0.f, hi = 0.f;
            if (grow >= 0 && grow < 64) {
                lo = xb[(size_t)c0 * HW + grow * 64 + lane];
                hi = xb[(size_t)(c0 + 1) * HW + grow * 64 + lane];
            }
            unsigned int u;
            asm volatile("v_cvt_pk_bf16_f32 %0, %1, %2" : "=v"(u) : "v"(lo), "v"(hi));
            int s = row * 66 + 1 + lane;
            int word = s * 16 + (((p >> 2) ^ ((s >> 1) & 3)) << 2) + (p & 3);
            xs[word] = u;
        }
        __syncthreads();

        // ---- compute: 9 taps x (4 A-frags, 8 B-frags, 32 MFMA) per wave ----
        int wrow = wid * 2;
        #pragma unroll
        for (int t9 = 0; t9 < 9; ++t9) {
            int di = t9 / 3, dj = t9 - di * 3;
            int abase = (t9 * 4 + g) * 256 + l15 * 4;
            short8 a0 = *(short8*)&as[abase + 0 * 64];
            short8 a1 = *(short8*)&as[abase + 1 * 64];
            short8 a2 = *(short8*)&as[abase + 2 * 64];
            short8 a3 = *(short8*)&as[abase + 3 * 64];
            #pragma unroll
            for (int f = 0; f < 8; ++f) {
                int s = (wrow + (f >> 2) + di) * 66 + (f & 3) * 16 + l15 + dj;
                short8 bb = *(short8*)&xs[s * 16 + ((g ^ ((s >> 1) & 3)) << 2)];
                acc[0][f] = __builtin_amdgcn_mfma_f32_16x16x32_bf16(a0, bb, acc[0][f], 0, 0, 0);
                acc[1][f] = __builtin_amdgcn_mfma_f32_16x16x32_bf16(a1, bb, acc[1][f], 0, 0, 0);
                acc[2][f] = __builtin_amdgcn_mfma_f32_16x16x32_bf16(a2, bb, acc[2][f], 0, 0, 0);
                acc[3][f] = __builtin_amdgcn_mfma_f32_16x16x32_bf16(a3, bb, acc[3][f], 0, 0, 0);
            }
        }
        __syncthreads();
    }

    // ---- epilogue: C layout col=lane&15 (pos), row=g*4+j (o) ----
    #pragma unroll
    for (int mi = 0; mi < 4; ++mi) {
        #pragma unroll
        for (int f = 0; f < 8; ++f) {
            int pos = (r0 + wid * 2 + (f >> 2)) * 64 + (f & 3) * 16 + l15;
            float* op = out + ((size_t)(b * COUT + o0 + mi * 16 + g * 4)) * HW + pos;
            #pragma unroll
            for (int j = 0; j < 4; ++j) op[(size_t)j * HW] = acc[mi][f][j];
        }
    }
}

extern "C" void kernel_launch(void* const* d_in, const int* in_sizes, int n_in,
                              void* d_out, int out_size, void* d_ws, size_t ws_size,
                              hipStream_t stream) {
    const float* x      = (const float*)d_in[0];
    const float* w1     = (const float*)d_in[1];
    const float* b1     = (const float*)d_in[2];
    const float* w2     = (const float*)d_in[3];
    const float* b2     = (const float*)d_in[4];
    const float* weight = (const float*)d_in[5];
    float* out = (float*)d_out;

    float*  ws     = (float*)d_ws;
    float*  pooled = ws;                         // 4096 f
    float*  rw     = ws + 4096;                  // 16384 f
    ushort* cw     = (ushort*)(ws + 4096 + 16384);  // 9437184 bf16 (~18.9 MB)

    pool_kernel<<<BB * CIN, 256, 0, stream>>>(x, pooled);
    route_kernel<<<1, 256, 0, stream>>>(pooled, w1, b1, w2, b2, rw);
    combine_kernel<<<288, 256, 0, stream>>>(rw, weight, cw);
    conv_mfma<<<512, 256, 0, stream>>>(x, cw, out);
}

// Round 3
// 193.043 us; speedup vs baseline: 6.7350x; 1.1557x over previous
//
#include <hip/hip_runtime.h>
#include <hip/hip_bf16.h>
#include <math.h>

#define BB   16
#define CIN  256
#define HH   64
#define WW   64
#define COUT 256
#define NEXP 4
#define REDC 16
#define HW   (HH*WW)       // 4096

typedef __attribute__((ext_vector_type(8))) short short8;
typedef __attribute__((ext_vector_type(4))) float f32x4;

#define AS1 __attribute__((address_space(1)))
#define AS3 __attribute__((address_space(3)))

__device__ __forceinline__ void gld_lds16(void* lds, const void* gp) {
    __builtin_amdgcn_global_load_lds((const AS1 unsigned int*)gp,
                                     (AS3 unsigned int*)lds, 16, 0, 0);
}

// -------- K0: x (f32, [b][c][s]) -> xT (bf16, [b][s][c]) + pooled partials --------
// grid: b(16) x chunk(8) x sq(4) = 512 blocks, 256 thr.
__global__ __launch_bounds__(256)
void transpose_pool_kernel(const float* __restrict__ x, ushort* __restrict__ xT,
                           float* __restrict__ pp) {
    int blk = blockIdx.x;
    int sq = blk & 3;
    int chunk = (blk >> 2) & 7;
    int b = blk >> 5;
    int c0 = chunk * 32;
    int s0 = sq * 1024;
    int tid = threadIdx.x;
    const float* xb = x + ((size_t)(b * CIN + c0)) * HW;
    ushort* xTb = xT + (size_t)b * HW * CIN;

    float psum[32];
    #pragma unroll
    for (int i = 0; i < 32; ++i) psum[i] = 0.f;

    for (int it = 0; it < 4; ++it) {
        int s = s0 + it * 256 + tid;
        unsigned int pk[16];
        #pragma unroll
        for (int p = 0; p < 16; ++p) {
            float lo = xb[(size_t)(2 * p) * HW + s];
            float hi = xb[(size_t)(2 * p + 1) * HW + s];
            psum[2 * p]     += lo;
            psum[2 * p + 1] += hi;
            asm volatile("v_cvt_pk_bf16_f32 %0, %1, %2" : "=v"(pk[p]) : "v"(lo), "v"(hi));
        }
        uint4* dst = (uint4*)(xTb + (size_t)s * CIN + c0);
        #pragma unroll
        for (int q = 0; q < 4; ++q)
            dst[q] = make_uint4(pk[q * 4], pk[q * 4 + 1], pk[q * 4 + 2], pk[q * 4 + 3]);
    }

    __shared__ float red[4][32];
    int lane = tid & 63, wid = tid >> 6;
    #pragma unroll
    for (int i = 0; i < 32; ++i) {
        float v = psum[i];
        #pragma unroll
        for (int off = 32; off > 0; off >>= 1) v += __shfl_down(v, off, 64);
        if (lane == 0) red[wid][i] = v;
    }
    __syncthreads();
    if (tid < 32)
        pp[(b * 4 + sq) * 256 + c0 + tid] = red[0][tid] + red[1][tid] + red[2][tid] + red[3][tid];
}

// ---------------- K2: routing MLP -> rw[b*1024 + k*256 + c] ----------------
__global__ void route_kernel(const float* __restrict__ pp,
                             const float* __restrict__ w1, const float* __restrict__ b1,
                             const float* __restrict__ w2, const float* __restrict__ b2,
                             float* __restrict__ rw) {
    __shared__ float p_s[BB][CIN];
    __shared__ float r_s[BB][REDC];
    int tid = threadIdx.x;
    for (int i = tid; i < BB * CIN; i += 256) {
        int b = i >> 8, c = i & 255;
        p_s[b][c] = (pp[(b * 4 + 0) * 256 + c] + pp[(b * 4 + 1) * 256 + c] +
                     pp[(b * 4 + 2) * 256 + c] + pp[(b * 4 + 3) * 256 + c]) * (1.0f / HW);
    }
    __syncthreads();
    {
        int b = tid >> 4, j = tid & 15;
        float acc = b1[j];
        for (int c = 0; c < CIN; ++c) acc += p_s[b][c] * w1[j * CIN + c];
        r_s[b][j] = fmaxf(acc, 0.f);
    }
    __syncthreads();
    for (int i = tid; i < BB * NEXP * CIN; i += 256) {
        int b = i >> 10, o2 = i & 1023;
        float acc = b2[o2];
        #pragma unroll
        for (int j = 0; j < REDC; ++j) acc += r_s[b][j] * w2[o2 * REDC + j];
        rw[i] = 1.f / (1.f + expf(-acc));
    }
}

// ------- K3: combined weights in MFMA fragment layout, bf16 -------
__global__ void combine_kernel(const float* __restrict__ rw,
                               const float* __restrict__ weight,
                               ushort* __restrict__ cw) {
    int cb = blockIdx.x;          // 288 blocks = (ot 4) x (chunk 8) x (t9 9)
    int t9 = cb % 9;
    int tmp = cb / 9;
    int chunk = tmp & 7;
    int ot = tmp >> 3;
    __shared__ float rw_s[BB][NEXP][32];
    int tid = threadIdx.x;
    for (int i = tid; i < BB * NEXP * 32; i += 256) {
        int b = i >> 7, r = i & 127, k = r >> 5, cc = r & 31;
        rw_s[b][k][cc] = rw[b * 1024 + k * 256 + chunk * 32 + cc];
    }
    __syncthreads();
    for (int h = 0; h < 2; ++h) {
        int t = h * 256 + tid;            // 0..511 = o_loc*8 + c8
        int o_loc = t >> 3, c8 = t & 7;
        int o = ot * 64 + o_loc;
        #pragma unroll
        for (int g = 0; g < 4; ++g) {
            int c = chunk * 32 + g * 8 + c8;
            int cl = g * 8 + c8;
            float w0 = weight[((size_t)(0 * COUT + o) * CIN + c) * 9 + t9];
            float w1 = weight[((size_t)(1 * COUT + o) * CIN + c) * 9 + t9];
            float w2 = weight[((size_t)(2 * COUT + o) * CIN + c) * 9 + t9];
            float w3 = weight[((size_t)(3 * COUT + o) * CIN + c) * 9 + t9];
            for (int b = 0; b < BB; ++b) {
                float acc = rw_s[b][0][cl] * w0 + rw_s[b][1][cl] * w1 +
                            rw_s[b][2][cl] * w2 + rw_s[b][3][cl] * w3;
                __hip_bfloat16 hv = __float2bfloat16(acc);
                size_t idx = (((size_t)((b * 4 + ot) * 8 + chunk) * 9 + t9) * 4 + g) * 512 + t;
                cw[idx] = *(ushort*)&hv;
            }
        }
    }
}

// ---------------- K4: MFMA implicit-GEMM conv ----------------
// block: 256 thr (4 waves). tile: 64 out-ch x (8 rows x 64 cols).
// xs: [s = row*66+col][4 slots of 16B], slot sigma = g ^ ((s>>1)&3) holds
// channel-group g. Staged DIRECTLY from xT via global_load_lds (linear dest,
// inverse-swizzled per-lane source). as: A frags, contiguous from cw.
__global__ __launch_bounds__(256, 2)
void conv_mfma(const ushort* __restrict__ xT, const ushort* __restrict__ cw,
               float* __restrict__ out) {
    __shared__ unsigned int xs[10560];   // 660 s * 16 words = 42240 B
    __shared__ unsigned int as[9216];    // 36 KB

    int hw = blockIdx.x;
    int L = (hw & 7) * 64 + (hw >> 3);   // XCD-chunked swizzle (512 = 8*64)
    int b  = L >> 5;
    int rt = (L >> 2) & 7;
    int ot = L & 3;
    int r0 = rt * 8, o0 = ot * 64;
    int tid  = threadIdx.x;
    int lane = tid & 63, wid = tid >> 6;
    int l15  = lane & 15, g = lane >> 4;

    for (int i = tid; i < 10560; i += 256) xs[i] = 0;

    f32x4 acc[4][8];
    #pragma unroll
    for (int mi = 0; mi < 4; ++mi)
        #pragma unroll
        for (int f = 0; f < 8; ++f) acc[mi][f] = (f32x4)0.f;

    const ushort* xTb = xT + (size_t)b * HW * CIN;
    const ushort* Ab  = cw + (size_t)((b * 4 + ot) * 8) * 18432;

    __syncthreads();

    for (int chunk = 0; chunk < 8; ++chunk) {
        // ---- stage A: contiguous 36 KB -> LDS ----
        const ushort* Ac = Ab + (size_t)chunk * 18432;
        #pragma unroll
        for (int k2 = 0; k2 < 9; ++k2) {
            int blk16 = k2 * 4 + wid;
            gld_lds16(&as[blk16 * 256],
                      (const char*)Ac + (size_t)blk16 * 1024 + lane * 16);
        }
        // ---- stage x: 10 rows x 4 col-quarters, 1 KB per gld ----
        #pragma unroll
        for (int i = 0; i < 10; ++i) {
            int q = i * 4 + wid;             // wave-uniform 0..39
            int r = q >> 2, cq = q & 3;
            int grow = r0 - 1 + r;
            if (grow >= 0 && grow < 64) {
                int sbase = r * 66 + 1 + cq * 16;
                int s_l   = sbase + (lane >> 2);
                int sigma = (lane & 3) ^ ((s_l >> 1) & 3);
                const ushort* src = xTb
                    + (size_t)(grow * 64 + cq * 16 + (lane >> 2)) * CIN
                    + chunk * 32 + sigma * 8;
                gld_lds16(&xs[sbase * 16], src);
            }
        }
        __syncthreads();

        // ---- compute: 9 taps x (4 A-frags, 8 B-frags, 32 MFMA) per wave ----
        int wrow = wid * 2;
        #pragma unroll
        for (int t9 = 0; t9 < 9; ++t9) {
            int di = t9 / 3, dj = t9 - di * 3;
            int abase = (t9 * 4 + g) * 256 + l15 * 4;
            short8 a0 = *(short8*)&as[abase + 0 * 64];
            short8 a1 = *(short8*)&as[abase + 1 * 64];
            short8 a2 = *(short8*)&as[abase + 2 * 64];
            short8 a3 = *(short8*)&as[abase + 3 * 64];
            #pragma unroll
            for (int f = 0; f < 8; ++f) {
                int s = (wrow + (f >> 2) + di) * 66 + (f & 3) * 16 + l15 + dj;
                short8 bb = *(short8*)&xs[s * 16 + ((g ^ ((s >> 1) & 3)) << 2)];
                acc[0][f] = __builtin_amdgcn_mfma_f32_16x16x32_bf16(a0, bb, acc[0][f], 0, 0, 0);
                acc[1][f] = __builtin_amdgcn_mfma_f32_16x16x32_bf16(a1, bb, acc[1][f], 0, 0, 0);
                acc[2][f] = __builtin_amdgcn_mfma_f32_16x16x32_bf16(a2, bb, acc[2][f], 0, 0, 0);
                acc[3][f] = __builtin_amdgcn_mfma_f32_16x16x32_bf16(a3, bb, acc[3][f], 0, 0, 0);
            }
        }
        __syncthreads();
    }

    // ---- epilogue ----
    #pragma unroll
    for (int mi = 0; mi < 4; ++mi) {
        #pragma unroll
        for (int f = 0; f < 8; ++f) {
            int pos = (r0 + wid * 2 + (f >> 2)) * 64 + (f & 3) * 16 + l15;
            float* op = out + ((size_t)(b * COUT + o0 + mi * 16 + g * 4)) * HW + pos;
            #pragma unroll
            for (int j = 0; j < 4; ++j) op[(size_t)j * HW] = acc[mi][f][j];
        }
    }
}

extern "C" void kernel_launch(void* const* d_in, const int* in_sizes, int n_in,
                              void* d_out, int out_size, void* d_ws, size_t ws_size,
                              hipStream_t stream) {
    const float* x      = (const float*)d_in[0];
    const float* w1     = (const float*)d_in[1];
    const float* b1     = (const float*)d_in[2];
    const float* w2     = (const float*)d_in[3];
    const float* b2     = (const float*)d_in[4];
    const float* weight = (const float*)d_in[5];
    float* out = (float*)d_out;

    float*  ws = (float*)d_ws;
    float*  pp = ws;                              // 16384 f
    float*  rw = ws + 16384;                      // 16384 f
    ushort* cw = (ushort*)(ws + 32768);           // 9437184 ushort (~18.9 MB)
    ushort* xT = (ushort*)(ws + 32768 + 4718592); // 16777216 ushort (~33.6 MB)

    transpose_pool_kernel<<<512, 256, 0, stream>>>(x, xT, pp);
    route_kernel<<<1, 256, 0, stream>>>(pp, w1, b1, w2, b2, rw);
    combine_kernel<<<288, 256, 0, stream>>>(rw, weight, cw);
    conv_mfma<<<512, 256, 0, stream>>>(xT, cw, out);
}